// Round 1
// baseline (1141.594 us; speedup 1.0000x reference)
//
#include <hip/hip_runtime.h>
#include <math.h>

#define Bn 8
#define Nn 256
#define Dn 3
#define Fn 32
#define NRBF 50
#define Hn 128
#define NK 255            // N-1 neighbors
#define ROW 8960          // N*(D+F)
#define EPSf 1e-6f

// ---------------------------------------------------------------------------
// Setup: interleave rbf-block weights as float4 {s1_W1, s1_W1*mu, s2_W1, f_W1}
// laid out [h][m] so the hot loop reads them with wave-uniform (scalar) loads.
// ---------------------------------------------------------------------------
__global__ __launch_bounds__(256) void setup_w4_kernel(
    const float* __restrict__ s1_W1, const float* __restrict__ s2_W1,
    const float* __restrict__ f_W1,  const float* __restrict__ mus,
    float4* __restrict__ W4)
{
    int idx = blockIdx.x * 256 + threadIdx.x;   // idx = h*NRBF + m
    if (idx >= Hn * NRBF) return;
    int h = idx / NRBF, m = idx - h * NRBF;
    float w1 = s1_W1[m * Hn + h];
    W4[idx] = make_float4(w1, w1 * mus[m], s2_W1[m * Hn + h], f_W1[m * Hn + h]);
}

// ---------------------------------------------------------------------------
// Main: one block per (b,i); lane tid = neighbor k (tid 255 masked).
// ---------------------------------------------------------------------------
__global__ __launch_bounds__(256) void pair_kernel(
    const float* __restrict__ state,
    const float* __restrict__ mus,   const float* __restrict__ gammap,
    const float* __restrict__ s1_W1, const float* __restrict__ s1_b1,
    const float* __restrict__ s1_W2, const float* __restrict__ s1_b2,
    const float* __restrict__ s2_W1, const float* __restrict__ s2_b1,
    const float* __restrict__ s2_W2, const float* __restrict__ s2_b2,
    const float* __restrict__ f_W1,  const float* __restrict__ f_b1,
    const float* __restrict__ f_W2,  const float* __restrict__ f_b2,
    const float4* __restrict__ W4,
    float* __restrict__ vx_pre, float* __restrict__ tr_part,
    float* __restrict__ out)
{
    const int i = blockIdx.x, b = blockIdx.y;
    const int tid = threadIdx.x;

    __shared__ float xpos[Nn * 3];
    __shared__ float ff[Fn];
    __shared__ float sf[Fn];
    __shared__ float zf1s[Hn], zf2s[Hn], zffs[Hn];
    __shared__ float afsum[4][Hn];
    __shared__ float red[4][8];
    __shared__ float afsL[Hn];

    // stage positions + self feats
    for (int t = tid; t < Nn * 3; t += 256) xpos[t] = state[b * ROW + t];
    if (tid < Fn) ff[tid] = state[b * ROW + Nn * Dn + i * Fn + tid];
    __syncthreads();

    // softmax(feats) — tiny, done redundantly by 32 threads
    if (tid < Fn) {
        float mx = -1e30f;
        for (int f = 0; f < Fn; f++) mx = fmaxf(mx, ff[f]);
        sf[tid] = __expf(ff[tid] - mx);
    }
    __syncthreads();
    float ssum = 0.f;
    if (tid < Fn) { for (int f = 0; f < Fn; f++) ssum += sf[f]; }
    __syncthreads();
    if (tid < Fn) sf[tid] = sf[tid] / ssum;
    __syncthreads();

    // per-(b,i) feature half of layer 1 (k-independent):
    // inp = [rbf, feats_i, other_feats=feats_i] -> feats contributes via rows
    // [50:82] + [82:114]; f-MLP uses softmax(feats) via rows [50:82].
    if (tid < Hn) {
        int h = tid;
        float z1 = s1_b1[h], z2 = s2_b1[h], zf = f_b1[h];
        for (int f = 0; f < Fn; f++) {
            float fv = ff[f];
            z1 += fv * (s1_W1[(NRBF + f) * Hn + h] + s1_W1[(NRBF + Fn + f) * Hn + h]);
            z2 += fv * (s2_W1[(NRBF + f) * Hn + h] + s2_W1[(NRBF + Fn + f) * Hn + h]);
            zf += sf[f] * f_W1[(NRBF + f) * Hn + h];
        }
        zf1s[h] = z1; zf2s[h] = z2; zffs[h] = zf;
    }
    __syncthreads();

    const float gamma = gammap[0];
    const int   k     = (tid < NK) ? tid : NK - 1;
    const float valid = (tid < NK) ? 1.f : 0.f;
    const int   j     = k + (k >= i ? 1 : 0);       // OFFD[i][k]

    float rx = xpos[i * 3 + 0] - xpos[j * 3 + 0];
    float ry = xpos[i * 3 + 1] - xpos[j * 3 + 1];
    float rz = xpos[i * 3 + 2] - xpos[j * 3 + 2];
    float ssq = rx * rx + ry * ry + rz * rz;
    float dd  = sqrtf(ssq + EPSf);

    float rb[NRBF];
    #pragma unroll
    for (int m = 0; m < NRBF; m++) {
        float t = dd - mus[m];
        rb[m] = __expf(-gamma * t * t);
    }

    float s1acc = 0.f, ds1acc = 0.f, s2acc = 0.f;
    const float n2g = -2.f * gamma;
    const int wv = tid >> 6;

    for (int h = 0; h < Hn; ++h) {
        float zr1 = 0.f, zmu = 0.f, zr2 = 0.f, zrf = 0.f;
        const float4* wp = W4 + h * NRBF;   // wave-uniform -> s_load
        #pragma unroll
        for (int m = 0; m < NRBF; m++) {
            float4 w = wp[m];
            zr1 = fmaf(rb[m], w.x, zr1);
            zmu = fmaf(rb[m], w.y, zmu);
            zr2 = fmaf(rb[m], w.z, zr2);
            zrf = fmaf(rb[m], w.w, zrf);
        }
        float z1  = zr1 + zf1s[h];
        float z2  = zr2 + zf2s[h];
        float zfv = zrf + zffs[h];

        float sig1 = 1.f / (1.f + __expf(-z1));
        float a1   = z1 * sig1;
        float w21  = s1_W2[h];
        s1acc = fmaf(a1, w21, s1acc);
        // exact d s1 / d d: silu'(z1) * dz1/dd, dz1/dd = -2g*(d*zr1 - zmu)
        float sp1 = sig1 * (1.f + z1 * (1.f - sig1));
        float dz1 = n2g * (dd * zr1 - zmu);
        ds1acc = fmaf(w21 * sp1, dz1, ds1acc);

        float sig2 = 1.f / (1.f + __expf(-z2));
        s2acc = fmaf(z2 * sig2, s2_W2[h], s2acc);

        float sigf = 1.f / (1.f + __expf(-zfv));
        float af = zfv * sigf * valid;
        #pragma unroll
        for (int off = 32; off; off >>= 1) af += __shfl_down(af, off, 64);
        if ((tid & 63) == 0) afsum[wv][h] = af;
    }

    float s1  = s1acc + s1_b2[0];
    float s2v = s2acc + s2_b2[0];
    float gd  = ds1acc * (ssq / dd);      // r2d = |r|^2 / d

    float vals[7];
    vals[0] = rx * s1 * valid;  vals[1] = ry * s1 * valid;  vals[2] = rz * s1 * valid;
    vals[3] = rx * s2v * valid; vals[4] = ry * s2v * valid; vals[5] = rz * s2v * valid;
    vals[6] = (gd + 3.f * s1) * valid;    // gd + D*s1 (trace integrand)

    #pragma unroll
    for (int c = 0; c < 7; c++) {
        float v = vals[c];
        #pragma unroll
        for (int off = 32; off; off >>= 1) v += __shfl_down(v, off, 64);
        if ((tid & 63) == 0) red[wv][c] = v;
    }
    __syncthreads();

    if (tid == 0) {
        float s[7];
        #pragma unroll
        for (int c = 0; c < 7; c++) s[c] = red[0][c] + red[1][c] + red[2][c] + red[3][c];
        const float inv = 1.f / 255.f;
        float vx0 = s[0] * inv, vx1 = s[1] * inv, vx2 = s[2] * inv;
        // vx += cross(S2R, vx)/255   (rr = r x vx is linear in r)
        float cx = (s[4] * vx2 - s[5] * vx1) * inv;
        float cy = (s[5] * vx0 - s[3] * vx2) * inv;
        float cz = (s[3] * vx1 - s[4] * vx0) * inv;
        int bi = b * Nn + i;
        vx_pre[bi * 4 + 0] = vx0 + cx;
        vx_pre[bi * 4 + 1] = vx1 + cy;
        vx_pre[bi * 4 + 2] = vx2 + cz;
        tr_part[bi] = s[6];
    }

    // deferred f second layer: v_feats = (sum_k silu(zf))/255 @ f_W2 + f_b2
    if (tid < Hn)
        afsL[tid] = (afsum[0][tid] + afsum[1][tid] + afsum[2][tid] + afsum[3][tid]) * (1.f / 255.f);
    __syncthreads();
    if (tid < Fn) {
        float acc = f_b2[tid];
        for (int h = 0; h < Hn; h++) acc = fmaf(afsL[h], f_W2[h * Fn + tid], acc);
        out[b * ROW + Nn * Dn + i * Fn + tid] = acc;
    }
}

// ---------------------------------------------------------------------------
// Finalize: remove mean over i from v_x, reduce trace per batch.
// ---------------------------------------------------------------------------
__global__ __launch_bounds__(256) void finalize_kernel(
    const float* __restrict__ vx_pre, const float* __restrict__ tr_part,
    float* __restrict__ out)
{
    int b = blockIdx.x, tid = threadIdx.x;
    int bi = b * Nn + tid;
    float v0 = vx_pre[bi * 4 + 0];
    float v1 = vx_pre[bi * 4 + 1];
    float v2 = vx_pre[bi * 4 + 2];
    float tr = tr_part[bi];

    __shared__ float red[4][4];
    __shared__ float fin[4];
    float vals[4] = {v0, v1, v2, tr};
    #pragma unroll
    for (int c = 0; c < 4; c++) {
        float v = vals[c];
        #pragma unroll
        for (int off = 32; off; off >>= 1) v += __shfl_down(v, off, 64);
        if ((tid & 63) == 0) red[tid >> 6][c] = v;
    }
    __syncthreads();
    if (tid < 4) fin[tid] = red[0][tid] + red[1][tid] + red[2][tid] + red[3][tid];
    __syncthreads();

    out[b * ROW + tid * 3 + 0] = v0 - fin[0] * (1.f / 256.f);
    out[b * ROW + tid * 3 + 1] = v1 - fin[1] * (1.f / 256.f);
    out[b * ROW + tid * 3 + 2] = v2 - fin[2] * (1.f / 256.f);
    if (tid == 0) out[Bn * ROW + b] = fin[3] * (1.f / 255.f);  // trace
}

// ---------------------------------------------------------------------------
extern "C" void kernel_launch(void* const* d_in, const int* in_sizes, int n_in,
                              void* d_out, int out_size, void* d_ws, size_t ws_size,
                              hipStream_t stream)
{
    const float* state = (const float*)d_in[1];
    const float* mus   = (const float*)d_in[2];
    const float* gam   = (const float*)d_in[3];
    const float* s1_W1 = (const float*)d_in[4];
    const float* s1_b1 = (const float*)d_in[5];
    const float* s1_W2 = (const float*)d_in[6];
    const float* s1_b2 = (const float*)d_in[7];
    const float* s2_W1 = (const float*)d_in[8];
    const float* s2_b1 = (const float*)d_in[9];
    const float* s2_W2 = (const float*)d_in[10];
    const float* s2_b2 = (const float*)d_in[11];
    const float* f_W1  = (const float*)d_in[12];
    const float* f_b1  = (const float*)d_in[13];
    const float* f_W2  = (const float*)d_in[14];
    const float* f_b2  = (const float*)d_in[15];

    float4* W4      = (float4*)d_ws;                                   // 102400 B
    float*  vx_pre  = (float*)((char*)d_ws + Hn * NRBF * sizeof(float4)); // 32768 B
    float*  tr_part = vx_pre + Bn * Nn * 4;                            // 8192 B
    float*  out     = (float*)d_out;

    setup_w4_kernel<<<(Hn * NRBF + 255) / 256, 256, 0, stream>>>(s1_W1, s2_W1, f_W1, mus, W4);

    dim3 grid(Nn, Bn);
    pair_kernel<<<grid, 256, 0, stream>>>(state, mus, gam,
        s1_W1, s1_b1, s1_W2, s1_b2,
        s2_W1, s2_b1, s2_W2, s2_b2,
        f_W1, f_b1, f_W2, f_b2,
        W4, vx_pre, tr_part, out);

    finalize_kernel<<<Bn, 256, 0, stream>>>(vx_pre, tr_part, out);
}

// Round 2
// 233.441 us; speedup vs baseline: 4.8903x; 4.8903x over previous
//
#include <hip/hip_runtime.h>
#include <math.h>

#define Bn 8
#define Nn 256
#define Fn 32
#define NRBF 50
#define Hn 128
#define NK 255            // N-1 neighbors
#define ROW 8960          // N*(D+F)
#define EPSf 1e-6f
#define KP 64             // K padded 50 -> 64
#define ASTR 72           // LDS A row stride (bf16 elems); 144B = 36 banks -> 2-way max

typedef __attribute__((ext_vector_type(8))) __bf16 b8;
typedef __attribute__((ext_vector_type(4))) float f32x4;

// ---------------------------------------------------------------------------
// Pack the 4 rbf-row weight groups as bf16 Wb[g][h][KP] (k-contiguous, zero
// padded k>=50) so B-fragments (B[k=quad*8+j][n=lane&15]) are 16B loads.
// g: 0=s1_W1, 1=s1_W1*mu, 2=s2_W1, 3=f_W1
// ---------------------------------------------------------------------------
__global__ __launch_bounds__(256) void pack_w_kernel(
    const float* __restrict__ s1_W1, const float* __restrict__ s2_W1,
    const float* __restrict__ f_W1,  const float* __restrict__ mus,
    __bf16* __restrict__ Wb)
{
    int idx = blockIdx.x * 256 + threadIdx.x;     // g*Hn*KP + h*KP + k
    if (idx >= 4 * Hn * KP) return;
    int g = idx >> 13;            // /(Hn*KP)
    int h = (idx >> 6) & 127;
    int k = idx & 63;
    float v = 0.f;
    if (k < NRBF) {
        if (g == 0)      v = s1_W1[k * Hn + h];
        else if (g == 1) v = s1_W1[k * Hn + h] * mus[k];
        else if (g == 2) v = s2_W1[k * Hn + h];
        else             v = f_W1[k * Hn + h];
    }
    Wb[idx] = (__bf16)v;
}

// ---------------------------------------------------------------------------
// One block per (b,i): build rbf A[256x64] bf16 in LDS, then per-wave MFMA
// GEMM (M=64/wave, N=512, K=64) with fused silu/derivative epilogue.
// ---------------------------------------------------------------------------
__global__ __launch_bounds__(256, 2) void pair_kernel(
    const float* __restrict__ state,
    const float* __restrict__ mus,   const float* __restrict__ gammap,
    const float* __restrict__ s1_W1, const float* __restrict__ s1_b1,
    const float* __restrict__ s1_W2, const float* __restrict__ s1_b2,
    const float* __restrict__ s2_W1, const float* __restrict__ s2_b1,
    const float* __restrict__ s2_W2, const float* __restrict__ s2_b2,
    const float* __restrict__ f_W1,  const float* __restrict__ f_b1,
    const float* __restrict__ f_W2,  const float* __restrict__ f_b2,
    const __bf16* __restrict__ Wb,
    float* __restrict__ vx_pre, float* __restrict__ tr_part,
    float* __restrict__ out)
{
    const int i = blockIdx.x, b = blockIdx.y;
    const int tid  = threadIdx.x;
    const int w    = tid >> 6;
    const int lane = tid & 63;
    const int c    = lane & 15;       // C/D col, A m, B n
    const int q    = lane >> 4;       // quad

    __shared__ __attribute__((aligned(16))) __bf16 As[256 * ASTR];
    __shared__ float xpos[Nn * 3];
    __shared__ float musS[NRBF];
    __shared__ float ff[Fn], sf[Fn];
    __shared__ float zf1s[Hn], zf2s[Hn], zffs[Hn];
    __shared__ float sW2a[Hn], sW2b[Hn];
    __shared__ float dsh[256];
    __shared__ float rsh[256][4];     // rx, ry, rz, ssq
    __shared__ float afsumsh[Hn];
    __shared__ float accum7[8];

    // ---- stage + init ----
    for (int t = tid; t < Nn * 3; t += 256) xpos[t] = state[b * ROW + t];
    if (tid < Fn)   ff[tid] = state[b * ROW + Nn * 3 + i * Fn + tid];
    if (tid < NRBF) musS[tid] = mus[tid];
    if (tid < Hn) { sW2a[tid] = s1_W2[tid]; sW2b[tid] = s2_W2[tid]; afsumsh[tid] = 0.f; }
    if (tid < 8)    accum7[tid] = 0.f;
    __syncthreads();                                   // S1

    const float gamma = gammap[0];

    if (tid < Fn) {
        float mx = -1e30f;
        for (int f = 0; f < Fn; f++) mx = fmaxf(mx, ff[f]);
        sf[tid] = __expf(ff[tid] - mx);
    }

    // ---- rbf rows -> LDS (bf16), plus d/r/ssq ----
    {
        const float valid = (tid < NK) ? 1.f : 0.f;
        const int   kk    = (tid < NK) ? tid : 0;
        const int   j     = kk + (kk >= i ? 1 : 0);
        float rx = (xpos[i * 3 + 0] - xpos[j * 3 + 0]) * valid;
        float ry = (xpos[i * 3 + 1] - xpos[j * 3 + 1]) * valid;
        float rz = (xpos[i * 3 + 2] - xpos[j * 3 + 2]) * valid;
        float ssq = rx * rx + ry * ry + rz * rz;
        float dd  = sqrtf(ssq + EPSf);
        dsh[tid] = dd;
        rsh[tid][0] = rx; rsh[tid][1] = ry; rsh[tid][2] = rz; rsh[tid][3] = ssq;
        #pragma unroll
        for (int ch = 0; ch < 8; ch++) {
            b8 v;
            #pragma unroll
            for (int jj = 0; jj < 8; jj++) {
                int m = ch * 8 + jj;
                float rv = 0.f;
                if (m < NRBF) {
                    float t = dd - musS[m];
                    rv = __expf(-gamma * t * t) * valid;
                }
                v[jj] = (__bf16)rv;
            }
            *(b8*)&As[tid * ASTR + ch * 8] = v;
        }
    }
    __syncthreads();                                   // S2 (sf raw ready)

    float ssum = 0.f;
    if (tid < Fn) { for (int f = 0; f < Fn; f++) ssum += sf[f]; }
    __syncthreads();                                   // S3
    if (tid < Fn) sf[tid] = sf[tid] / ssum;
    __syncthreads();                                   // S4

    // k-independent feature halves of layer 1
    if (tid < Hn) {
        int h = tid;
        float z1 = s1_b1[h], z2 = s2_b1[h], zf = f_b1[h];
        for (int f = 0; f < Fn; f++) {
            float fv = ff[f];
            z1 += fv * (s1_W1[(NRBF + f) * Hn + h] + s1_W1[(NRBF + Fn + f) * Hn + h]);
            z2 += fv * (s2_W1[(NRBF + f) * Hn + h] + s2_W1[(NRBF + Fn + f) * Hn + h]);
            zf += sf[f] * f_W1[(NRBF + f) * Hn + h];
        }
        zf1s[h] = z1; zf2s[h] = z2; zffs[h] = zf;
    }
    __syncthreads();                                   // S5 — As, zf*, dsh, rsh ready

    // ---- per-wave GEMM + fused epilogue; wave w owns rows [w*64, w*64+64) ----
    const float n2g = -2.f * gamma;
    float dreg[16], n2gd[16];
    #pragma unroll
    for (int mc = 0; mc < 4; mc++)
        #pragma unroll
        for (int r = 0; r < 4; r++) {
            float dv = dsh[w * 64 + mc * 16 + q * 4 + r];
            dreg[mc * 4 + r] = dv;
            n2gd[mc * 4 + r] = n2g * dv;
        }

    float s1p[16], ds1p[16], s2p[16];
    #pragma unroll
    for (int t = 0; t < 16; t++) { s1p[t] = 0.f; ds1p[t] = 0.f; s2p[t] = 0.f; }

    // ---- pass 1: s1 (needs zr1 and zmu jointly) ----
    for (int nt = 0; nt < 8; nt++) {
        int h = nt * 16 + c;
        const b8* B0 = (const b8*)&Wb[(0 * Hn + h) * KP];
        const b8* B1 = (const b8*)&Wb[(1 * Hn + h) * KP];
        b8 b00 = B0[q], b01 = B0[4 + q];
        b8 b10 = B1[q], b11 = B1[4 + q];
        float w2  = sW2a[h];
        float zf1 = zf1s[h];
        #pragma unroll
        for (int mc = 0; mc < 4; mc++) {
            const b8* Ar = (const b8*)&As[(w * 64 + mc * 16 + c) * ASTR];
            b8 a0 = Ar[q], a1f = Ar[4 + q];
            f32x4 acc1 = {0.f, 0.f, 0.f, 0.f}, accm = {0.f, 0.f, 0.f, 0.f};
            acc1 = __builtin_amdgcn_mfma_f32_16x16x32_bf16(a0,  b00, acc1, 0, 0, 0);
            acc1 = __builtin_amdgcn_mfma_f32_16x16x32_bf16(a1f, b01, acc1, 0, 0, 0);
            accm = __builtin_amdgcn_mfma_f32_16x16x32_bf16(a0,  b10, accm, 0, 0, 0);
            accm = __builtin_amdgcn_mfma_f32_16x16x32_bf16(a1f, b11, accm, 0, 0, 0);
            #pragma unroll
            for (int r = 0; r < 4; r++) {
                int idx = mc * 4 + r;
                float zr1 = acc1[r], zmu = accm[r];
                float z1  = zr1 + zf1;
                float e   = __expf(-z1);
                float sig = 1.f / (1.f + e);
                float av  = z1 * sig;
                s1p[idx]  = fmaf(av, w2, s1p[idx]);
                float sp1 = sig * (1.f + z1 * (1.f - sig));
                float dz1 = fmaf(n2gd[idx], zr1, -(n2g * zmu));
                ds1p[idx] = fmaf(w2 * sp1, dz1, ds1p[idx]);
            }
        }
    }

    // ---- pass 2: s2 ----
    for (int nt = 0; nt < 8; nt++) {
        int h = nt * 16 + c;
        const b8* B2 = (const b8*)&Wb[(2 * Hn + h) * KP];
        b8 b20 = B2[q], b21 = B2[4 + q];
        float w2  = sW2b[h];
        float zf2 = zf2s[h];
        #pragma unroll
        for (int mc = 0; mc < 4; mc++) {
            const b8* Ar = (const b8*)&As[(w * 64 + mc * 16 + c) * ASTR];
            b8 a0 = Ar[q], a1f = Ar[4 + q];
            f32x4 acc = {0.f, 0.f, 0.f, 0.f};
            acc = __builtin_amdgcn_mfma_f32_16x16x32_bf16(a0,  b20, acc, 0, 0, 0);
            acc = __builtin_amdgcn_mfma_f32_16x16x32_bf16(a1f, b21, acc, 0, 0, 0);
            #pragma unroll
            for (int r = 0; r < 4; r++) {
                int idx = mc * 4 + r;
                float z2  = acc[r] + zf2;
                float sig = 1.f / (1.f + __expf(-z2));
                s2p[idx]  = fmaf(z2 * sig, w2, s2p[idx]);
            }
        }
    }

    // ---- butterfly h-reduction over col lanes (xor bits 0..3) ----
    #pragma unroll
    for (int off = 1; off < 16; off <<= 1) {
        #pragma unroll
        for (int t = 0; t < 16; t++) {
            s1p[t]  += __shfl_xor(s1p[t],  off, 64);
            ds1p[t] += __shfl_xor(ds1p[t], off, 64);
            s2p[t]  += __shfl_xor(s2p[t],  off, 64);
        }
    }

    // ---- per-row finalize: 4 lanes/wave, 16 rows each ----
    if (c == 0) {
        const float b2_1 = s1_b2[0], b2_2 = s2_b2[0];
        float p0 = 0.f, p1 = 0.f, p2 = 0.f, p3 = 0.f, p4 = 0.f, p5 = 0.f, p6 = 0.f;
        #pragma unroll
        for (int mc = 0; mc < 4; mc++)
            #pragma unroll
            for (int r = 0; r < 4; r++) {
                int idx = mc * 4 + r;
                int row = w * 64 + mc * 16 + q * 4 + r;
                if (row < NK) {
                    float s1  = s1p[idx] + b2_1;
                    float s2v = s2p[idx] + b2_2;
                    float gd  = ds1p[idx] * (rsh[row][3] / dreg[idx]);
                    float rx = rsh[row][0], ry = rsh[row][1], rz = rsh[row][2];
                    p0 += rx * s1;  p1 += ry * s1;  p2 += rz * s1;
                    p3 += rx * s2v; p4 += ry * s2v; p5 += rz * s2v;
                    p6 += gd + 3.f * s1;
                }
            }
        atomicAdd(&accum7[0], p0); atomicAdd(&accum7[1], p1);
        atomicAdd(&accum7[2], p2); atomicAdd(&accum7[3], p3);
        atomicAdd(&accum7[4], p4); atomicAdd(&accum7[5], p5);
        atomicAdd(&accum7[6], p6);
    }

    // ---- pass 3: f MLP hidden, reduce over rows k ----
    for (int nt = 0; nt < 8; nt++) {
        int h = nt * 16 + c;
        const b8* B3 = (const b8*)&Wb[(3 * Hn + h) * KP];
        b8 b30 = B3[q], b31 = B3[4 + q];
        float zff = zffs[h];
        float afp = 0.f;
        #pragma unroll
        for (int mc = 0; mc < 4; mc++) {
            const b8* Ar = (const b8*)&As[(w * 64 + mc * 16 + c) * ASTR];
            b8 a0 = Ar[q], a1f = Ar[4 + q];
            f32x4 acc = {0.f, 0.f, 0.f, 0.f};
            acc = __builtin_amdgcn_mfma_f32_16x16x32_bf16(a0,  b30, acc, 0, 0, 0);
            acc = __builtin_amdgcn_mfma_f32_16x16x32_bf16(a1f, b31, acc, 0, 0, 0);
            #pragma unroll
            for (int r = 0; r < 4; r++) {
                int row = w * 64 + mc * 16 + q * 4 + r;
                float z   = acc[r] + zff;
                float sig = 1.f / (1.f + __expf(-z));
                afp += (row < NK) ? z * sig : 0.f;
            }
        }
        afp += __shfl_xor(afp, 16, 64);
        afp += __shfl_xor(afp, 32, 64);
        if (lane < 16) atomicAdd(&afsumsh[h], afp);
    }
    __syncthreads();                                   // S6 — accum7 & afsumsh ready

    if (tid == 0) {
        const float inv = 1.f / 255.f;
        float vx0 = accum7[0] * inv, vx1 = accum7[1] * inv, vx2 = accum7[2] * inv;
        float cx = (accum7[4] * vx2 - accum7[5] * vx1) * inv;
        float cy = (accum7[5] * vx0 - accum7[3] * vx2) * inv;
        float cz = (accum7[3] * vx1 - accum7[4] * vx0) * inv;
        int bi = b * Nn + i;
        vx_pre[bi * 4 + 0] = vx0 + cx;
        vx_pre[bi * 4 + 1] = vx1 + cy;
        vx_pre[bi * 4 + 2] = vx2 + cz;
        tr_part[bi] = accum7[6];
    }

    // deferred f second layer
    if (tid < Fn) {
        float acc = 0.f;
        for (int h = 0; h < Hn; h++) acc = fmaf(afsumsh[h], f_W2[h * Fn + tid], acc);
        out[b * ROW + Nn * 3 + i * Fn + tid] = fmaf(acc, 1.f / 255.f, f_b2[tid]);
    }
}

// ---------------------------------------------------------------------------
__global__ __launch_bounds__(256) void finalize_kernel(
    const float* __restrict__ vx_pre, const float* __restrict__ tr_part,
    float* __restrict__ out)
{
    int b = blockIdx.x, tid = threadIdx.x;
    int bi = b * Nn + tid;
    float v0 = vx_pre[bi * 4 + 0];
    float v1 = vx_pre[bi * 4 + 1];
    float v2 = vx_pre[bi * 4 + 2];
    float tr = tr_part[bi];

    __shared__ float red[4][4];
    __shared__ float fin[4];
    float vals[4] = {v0, v1, v2, tr};
    #pragma unroll
    for (int cc = 0; cc < 4; cc++) {
        float v = vals[cc];
        #pragma unroll
        for (int off = 32; off; off >>= 1) v += __shfl_down(v, off, 64);
        if ((tid & 63) == 0) red[tid >> 6][cc] = v;
    }
    __syncthreads();
    if (tid < 4) fin[tid] = red[0][tid] + red[1][tid] + red[2][tid] + red[3][tid];
    __syncthreads();

    out[b * ROW + tid * 3 + 0] = v0 - fin[0] * (1.f / 256.f);
    out[b * ROW + tid * 3 + 1] = v1 - fin[1] * (1.f / 256.f);
    out[b * ROW + tid * 3 + 2] = v2 - fin[2] * (1.f / 256.f);
    if (tid == 0) out[Bn * ROW + b] = fin[3] * (1.f / 255.f);
}

// ---------------------------------------------------------------------------
extern "C" void kernel_launch(void* const* d_in, const int* in_sizes, int n_in,
                              void* d_out, int out_size, void* d_ws, size_t ws_size,
                              hipStream_t stream)
{
    const float* state = (const float*)d_in[1];
    const float* mus   = (const float*)d_in[2];
    const float* gam   = (const float*)d_in[3];
    const float* s1_W1 = (const float*)d_in[4];
    const float* s1_b1 = (const float*)d_in[5];
    const float* s1_W2 = (const float*)d_in[6];
    const float* s1_b2 = (const float*)d_in[7];
    const float* s2_W1 = (const float*)d_in[8];
    const float* s2_b1 = (const float*)d_in[9];
    const float* s2_W2 = (const float*)d_in[10];
    const float* s2_b2 = (const float*)d_in[11];
    const float* f_W1  = (const float*)d_in[12];
    const float* f_b1  = (const float*)d_in[13];
    const float* f_W2  = (const float*)d_in[14];
    const float* f_b2  = (const float*)d_in[15];

    __bf16* Wb     = (__bf16*)d_ws;                                   // 4*128*64*2 = 64 KiB
    float*  vx_pre = (float*)((char*)d_ws + 4 * Hn * KP * sizeof(__bf16));
    float*  tr_part = vx_pre + Bn * Nn * 4;
    float*  out    = (float*)d_out;

    pack_w_kernel<<<(4 * Hn * KP + 255) / 256, 256, 0, stream>>>(s1_W1, s2_W1, f_W1, mus, Wb);

    dim3 grid(Nn, Bn);
    pair_kernel<<<grid, 256, 0, stream>>>(state, mus, gam,
        s1_W1, s1_b1, s1_W2, s1_b2,
        s2_W1, s2_b1, s2_W2, s2_b2,
        f_W1, f_b1, f_W2, f_b2,
        Wb, vx_pre, tr_part, out);

    finalize_kernel<<<Bn, 256, 0, stream>>>(vx_pre, tr_part, out);
}

// Round 3
// 210.762 us; speedup vs baseline: 5.4165x; 1.1076x over previous
//
#include <hip/hip_runtime.h>
#include <math.h>

#define Bn 8
#define Nn 256
#define Fn 32
#define NRBF 50
#define Hn 128
#define NK 255            // N-1 neighbors
#define ROW 8960          // N*(D+F)
#define EPSf 1e-6f
#define KP 64             // K padded 50 -> 64
#define ASTR 72           // LDS A row stride (bf16 elems); 144B stride -> <=2-way conflict
#define L2E 1.44269504f

typedef __attribute__((ext_vector_type(8))) __bf16 b8;
typedef __attribute__((ext_vector_type(4))) float f32x4;

__device__ __forceinline__ float fast_sig(float z) {
    // sigmoid(z) = 1/(1+e^-z), via v_exp_f32 (2^x) + v_rcp_f32
    return __builtin_amdgcn_rcpf(1.f + __builtin_amdgcn_exp2f(-z * L2E));
}

// ---------------------------------------------------------------------------
// Pack the 4 rbf-row weight groups as bf16 Wb[g][h][KP] (k-contiguous, zero
// padded k>=50). g: 0=s1_W1, 1=s1_W1*mu, 2=s2_W1, 3=f_W1
// ---------------------------------------------------------------------------
__global__ __launch_bounds__(256) void pack_w_kernel(
    const float* __restrict__ s1_W1, const float* __restrict__ s2_W1,
    const float* __restrict__ f_W1,  const float* __restrict__ mus,
    __bf16* __restrict__ Wb)
{
    int idx = blockIdx.x * 256 + threadIdx.x;     // g*Hn*KP + h*KP + k
    if (idx >= 4 * Hn * KP) return;
    int g = idx >> 13;
    int h = (idx >> 6) & 127;
    int k = idx & 63;
    float v = 0.f;
    if (k < NRBF) {
        if (g == 0)      v = s1_W1[k * Hn + h];
        else if (g == 1) v = s1_W1[k * Hn + h] * mus[k];
        else if (g == 2) v = s2_W1[k * Hn + h];
        else             v = f_W1[k * Hn + h];
    }
    Wb[idx] = (__bf16)v;
}

// ---------------------------------------------------------------------------
// One block per (b,i): rbf A[256x64] bf16 in LDS, per-wave MFMA GEMM
// (M=64/wave, N=512, K=64) with lean fused epilogue.
// ---------------------------------------------------------------------------
__global__ __launch_bounds__(256, 2) void pair_kernel(
    const float* __restrict__ state,
    const float* __restrict__ mus,   const float* __restrict__ gammap,
    const float* __restrict__ s1_W1, const float* __restrict__ s1_b1,
    const float* __restrict__ s1_W2, const float* __restrict__ s1_b2,
    const float* __restrict__ s2_W1, const float* __restrict__ s2_b1,
    const float* __restrict__ s2_W2, const float* __restrict__ s2_b2,
    const float* __restrict__ f_W1,  const float* __restrict__ f_b1,
    const float* __restrict__ f_W2,  const float* __restrict__ f_b2,
    const __bf16* __restrict__ Wb,
    float* __restrict__ vx_pre, float* __restrict__ tr_part,
    float* __restrict__ out)
{
    const int i = blockIdx.x, b = blockIdx.y;
    const int tid  = threadIdx.x;
    const int w    = tid >> 6;
    const int lane = tid & 63;
    const int c    = lane & 15;       // C/D col, A m, B n
    const int q    = lane >> 4;       // quad

    __shared__ __attribute__((aligned(16))) __bf16 As[256 * ASTR];
    __shared__ float xpos[Nn * 3];
    __shared__ float musS[NRBF];
    __shared__ float ff[Fn], sf[Fn];
    __shared__ float zf1s[Hn], zf2s[Hn], zffs[Hn];
    __shared__ float sW2a[Hn], sW2b[Hn];
    __shared__ float dsh[256];
    __shared__ float rsh[256][4];     // rx, ry, rz, ssq
    __shared__ float afsumsh[Hn];
    __shared__ float accum7[8];

    for (int t = tid; t < Nn * 3; t += 256) xpos[t] = state[b * ROW + t];
    if (tid < Fn)   ff[tid] = state[b * ROW + Nn * 3 + i * Fn + tid];
    if (tid < NRBF) musS[tid] = mus[tid];
    if (tid < Hn) { sW2a[tid] = s1_W2[tid]; sW2b[tid] = s2_W2[tid]; afsumsh[tid] = 0.f; }
    if (tid < 8)    accum7[tid] = 0.f;
    __syncthreads();                                   // S1

    const float gamma = gammap[0];

    if (tid < Fn) {
        float mx = -1e30f;
        for (int f = 0; f < Fn; f++) mx = fmaxf(mx, ff[f]);
        sf[tid] = __builtin_amdgcn_exp2f((ff[tid] - mx) * L2E);
    }

    // rbf rows -> LDS (bf16), plus d/r/ssq
    {
        const float valid = (tid < NK) ? 1.f : 0.f;
        const int   kk    = (tid < NK) ? tid : 0;
        const int   j     = kk + (kk >= i ? 1 : 0);
        float rx = (xpos[i * 3 + 0] - xpos[j * 3 + 0]) * valid;
        float ry = (xpos[i * 3 + 1] - xpos[j * 3 + 1]) * valid;
        float rz = (xpos[i * 3 + 2] - xpos[j * 3 + 2]) * valid;
        float ssq = rx * rx + ry * ry + rz * rz;
        float dd  = sqrtf(ssq + EPSf);
        dsh[tid] = dd;
        rsh[tid][0] = rx; rsh[tid][1] = ry; rsh[tid][2] = rz; rsh[tid][3] = ssq;
        const float ngl = -gamma * L2E;
        #pragma unroll
        for (int ch = 0; ch < 8; ch++) {
            b8 v;
            #pragma unroll
            for (int jj = 0; jj < 8; jj++) {
                int m = ch * 8 + jj;
                float rv = 0.f;
                if (m < NRBF) {
                    float t = dd - musS[m];
                    rv = __builtin_amdgcn_exp2f(ngl * t * t) * valid;
                }
                v[jj] = (__bf16)rv;
            }
            *(b8*)&As[tid * ASTR + ch * 8] = v;
        }
    }
    __syncthreads();                                   // S2

    float ssum = 0.f;
    if (tid < Fn) { for (int f = 0; f < Fn; f++) ssum += sf[f]; }
    __syncthreads();                                   // S3
    if (tid < Fn) sf[tid] = sf[tid] * __builtin_amdgcn_rcpf(ssum);
    __syncthreads();                                   // S4

    if (tid < Hn) {
        int h = tid;
        float z1 = s1_b1[h], z2 = s2_b1[h], zf = f_b1[h];
        for (int f = 0; f < Fn; f++) {
            float fv = ff[f];
            z1 += fv * (s1_W1[(NRBF + f) * Hn + h] + s1_W1[(NRBF + Fn + f) * Hn + h]);
            z2 += fv * (s2_W1[(NRBF + f) * Hn + h] + s2_W1[(NRBF + Fn + f) * Hn + h]);
            zf += sf[f] * f_W1[(NRBF + f) * Hn + h];
        }
        zf1s[h] = z1; zf2s[h] = z2; zffs[h] = zf;
    }
    __syncthreads();                                   // S5 — everything staged

    // ---- hoist A-fragments into registers ONCE (reused by all 3 passes) ----
    b8 a0[4], a1[4];
    #pragma unroll
    for (int mc = 0; mc < 4; mc++) {
        const b8* Ar = (const b8*)&As[(w * 64 + mc * 16 + c) * ASTR];
        a0[mc] = Ar[q];
        a1[mc] = Ar[4 + q];
    }

    float dreg[16];
    #pragma unroll
    for (int mc = 0; mc < 4; mc++)
        #pragma unroll
        for (int r = 0; r < 4; r++)
            dreg[mc * 4 + r] = dsh[w * 64 + mc * 16 + q * 4 + r];

    float s1p[16], ds1p[16], s2p[16];
    #pragma unroll
    for (int t = 0; t < 16; t++) { s1p[t] = 0.f; ds1p[t] = 0.f; s2p[t] = 0.f; }

    // ---- pass 1: s1 + derivative ----
    for (int nt = 0; nt < 8; nt++) {
        int h = nt * 16 + c;
        const b8* B0 = (const b8*)&Wb[(0 * Hn + h) * KP];
        const b8* B1 = (const b8*)&Wb[(1 * Hn + h) * KP];
        b8 b00 = B0[q], b01 = B0[4 + q];
        b8 b10 = B1[q], b11 = B1[4 + q];
        float w2  = sW2a[h];
        float zf1 = zf1s[h];
        #pragma unroll
        for (int mc = 0; mc < 4; mc++) {
            f32x4 acc1 = {0.f, 0.f, 0.f, 0.f}, accm = {0.f, 0.f, 0.f, 0.f};
            acc1 = __builtin_amdgcn_mfma_f32_16x16x32_bf16(a0[mc], b00, acc1, 0, 0, 0);
            acc1 = __builtin_amdgcn_mfma_f32_16x16x32_bf16(a1[mc], b01, acc1, 0, 0, 0);
            accm = __builtin_amdgcn_mfma_f32_16x16x32_bf16(a0[mc], b10, accm, 0, 0, 0);
            accm = __builtin_amdgcn_mfma_f32_16x16x32_bf16(a1[mc], b11, accm, 0, 0, 0);
            #pragma unroll
            for (int r = 0; r < 4; r++) {
                int idx = mc * 4 + r;
                float zr1 = acc1[r];
                float z1  = zr1 + zf1;
                float sig = fast_sig(z1);
                s1p[idx]  = fmaf(z1 * sig, w2, s1p[idx]);
                // sp = sig*(1 + z1*(1-sig));  t = d*zr1 - zmu
                float sp  = sig * fmaf(z1, 1.f - sig, 1.f);
                float t   = fmaf(dreg[idx], zr1, -accm[r]);
                ds1p[idx] = fmaf(w2 * sp, t, ds1p[idx]);   // * n2g applied at end
            }
        }
    }

    // ---- pass 2: s2 ----
    for (int nt = 0; nt < 8; nt++) {
        int h = nt * 16 + c;
        const b8* B2 = (const b8*)&Wb[(2 * Hn + h) * KP];
        b8 b20 = B2[q], b21 = B2[4 + q];
        float w2  = sW2b[h];
        float zf2 = zf2s[h];
        #pragma unroll
        for (int mc = 0; mc < 4; mc++) {
            f32x4 acc = {0.f, 0.f, 0.f, 0.f};
            acc = __builtin_amdgcn_mfma_f32_16x16x32_bf16(a0[mc], b20, acc, 0, 0, 0);
            acc = __builtin_amdgcn_mfma_f32_16x16x32_bf16(a1[mc], b21, acc, 0, 0, 0);
            #pragma unroll
            for (int r = 0; r < 4; r++) {
                int idx = mc * 4 + r;
                float z2  = acc[r] + zf2;
                float sig = fast_sig(z2);
                s2p[idx]  = fmaf(z2 * sig, w2, s2p[idx]);
            }
        }
    }

    // ---- pass 3: f MLP hidden, reduce over rows k ----
    for (int nt = 0; nt < 8; nt++) {
        int h = nt * 16 + c;
        const b8* B3 = (const b8*)&Wb[(3 * Hn + h) * KP];
        b8 b30 = B3[q], b31 = B3[4 + q];
        float zff = zffs[h];
        float afp = 0.f;
        #pragma unroll
        for (int mc = 0; mc < 4; mc++) {
            f32x4 acc = {0.f, 0.f, 0.f, 0.f};
            acc = __builtin_amdgcn_mfma_f32_16x16x32_bf16(a0[mc], b30, acc, 0, 0, 0);
            acc = __builtin_amdgcn_mfma_f32_16x16x32_bf16(a1[mc], b31, acc, 0, 0, 0);
            #pragma unroll
            for (int r = 0; r < 4; r++) {
                int row = w * 64 + mc * 16 + q * 4 + r;
                float z   = acc[r] + zff;
                float av  = z * fast_sig(z);
                afp += (row < NK) ? av : 0.f;
            }
        }
        afp += __shfl_xor(afp, 16, 64);
        afp += __shfl_xor(afp, 32, 64);
        if (lane < 16) atomicAdd(&afsumsh[h], afp);
    }

    // ---- butterfly h-reduction over col lanes ----
    #pragma unroll
    for (int off = 1; off < 16; off <<= 1) {
        #pragma unroll
        for (int t = 0; t < 16; t++) {
            s1p[t]  += __shfl_xor(s1p[t],  off, 64);
            ds1p[t] += __shfl_xor(ds1p[t], off, 64);
            s2p[t]  += __shfl_xor(s2p[t],  off, 64);
        }
    }

    if (c == 0) {
        const float b2_1 = s1_b2[0], b2_2 = s2_b2[0];
        const float n2g  = -2.f * gamma;
        float p0 = 0.f, p1 = 0.f, p2 = 0.f, p3 = 0.f, p4 = 0.f, p5 = 0.f, p6 = 0.f;
        #pragma unroll
        for (int mc = 0; mc < 4; mc++)
            #pragma unroll
            for (int r = 0; r < 4; r++) {
                int idx = mc * 4 + r;
                int row = w * 64 + mc * 16 + q * 4 + r;
                if (row < NK) {
                    float s1  = s1p[idx] + b2_1;
                    float s2v = s2p[idx] + b2_2;
                    float gd  = ds1p[idx] * n2g * rsh[row][3] * __builtin_amdgcn_rcpf(dreg[idx]);
                    float rx = rsh[row][0], ry = rsh[row][1], rz = rsh[row][2];
                    p0 += rx * s1;  p1 += ry * s1;  p2 += rz * s1;
                    p3 += rx * s2v; p4 += ry * s2v; p5 += rz * s2v;
                    p6 += gd + 3.f * s1;
                }
            }
        atomicAdd(&accum7[0], p0); atomicAdd(&accum7[1], p1);
        atomicAdd(&accum7[2], p2); atomicAdd(&accum7[3], p3);
        atomicAdd(&accum7[4], p4); atomicAdd(&accum7[5], p5);
        atomicAdd(&accum7[6], p6);
    }
    __syncthreads();                                   // S6

    if (tid == 0) {
        const float inv = 1.f / 255.f;
        float vx0 = accum7[0] * inv, vx1 = accum7[1] * inv, vx2 = accum7[2] * inv;
        float cx = (accum7[4] * vx2 - accum7[5] * vx1) * inv;
        float cy = (accum7[5] * vx0 - accum7[3] * vx2) * inv;
        float cz = (accum7[3] * vx1 - accum7[4] * vx0) * inv;
        int bi = b * Nn + i;
        vx_pre[bi * 4 + 0] = vx0 + cx;
        vx_pre[bi * 4 + 1] = vx1 + cy;
        vx_pre[bi * 4 + 2] = vx2 + cz;
        tr_part[bi] = accum7[6];
    }

    if (tid < Fn) {
        float acc = 0.f;
        for (int h = 0; h < Hn; h++) acc = fmaf(afsumsh[h], f_W2[h * Fn + tid], acc);
        out[b * ROW + Nn * 3 + i * Fn + tid] = fmaf(acc, 1.f / 255.f, f_b2[tid]);
    }
}

// ---------------------------------------------------------------------------
__global__ __launch_bounds__(256) void finalize_kernel(
    const float* __restrict__ vx_pre, const float* __restrict__ tr_part,
    float* __restrict__ out)
{
    int b = blockIdx.x, tid = threadIdx.x;
    int bi = b * Nn + tid;
    float v0 = vx_pre[bi * 4 + 0];
    float v1 = vx_pre[bi * 4 + 1];
    float v2 = vx_pre[bi * 4 + 2];
    float tr = tr_part[bi];

    __shared__ float red[4][4];
    __shared__ float fin[4];
    float vals[4] = {v0, v1, v2, tr};
    #pragma unroll
    for (int cc = 0; cc < 4; cc++) {
        float v = vals[cc];
        #pragma unroll
        for (int off = 32; off; off >>= 1) v += __shfl_down(v, off, 64);
        if ((tid & 63) == 0) red[tid >> 6][cc] = v;
    }
    __syncthreads();
    if (tid < 4) fin[tid] = red[0][tid] + red[1][tid] + red[2][tid] + red[3][tid];
    __syncthreads();

    out[b * ROW + tid * 3 + 0] = v0 - fin[0] * (1.f / 256.f);
    out[b * ROW + tid * 3 + 1] = v1 - fin[1] * (1.f / 256.f);
    out[b * ROW + tid * 3 + 2] = v2 - fin[2] * (1.f / 256.f);
    if (tid == 0) out[Bn * ROW + b] = fin[3] * (1.f / 255.f);
}

// ---------------------------------------------------------------------------
extern "C" void kernel_launch(void* const* d_in, const int* in_sizes, int n_in,
                              void* d_out, int out_size, void* d_ws, size_t ws_size,
                              hipStream_t stream)
{
    const float* state = (const float*)d_in[1];
    const float* mus   = (const float*)d_in[2];
    const float* gam   = (const float*)d_in[3];
    const float* s1_W1 = (const float*)d_in[4];
    const float* s1_b1 = (const float*)d_in[5];
    const float* s1_W2 = (const float*)d_in[6];
    const float* s1_b2 = (const float*)d_in[7];
    const float* s2_W1 = (const float*)d_in[8];
    const float* s2_b1 = (const float*)d_in[9];
    const float* s2_W2 = (const float*)d_in[10];
    const float* s2_b2 = (const float*)d_in[11];
    const float* f_W1  = (const float*)d_in[12];
    const float* f_b1  = (const float*)d_in[13];
    const float* f_W2  = (const float*)d_in[14];
    const float* f_b2  = (const float*)d_in[15];

    __bf16* Wb     = (__bf16*)d_ws;                                   // 64 KiB
    float*  vx_pre = (float*)((char*)d_ws + 4 * Hn * KP * sizeof(__bf16));
    float*  tr_part = vx_pre + Bn * Nn * 4;
    float*  out    = (float*)d_out;

    pack_w_kernel<<<(4 * Hn * KP + 255) / 256, 256, 0, stream>>>(s1_W1, s2_W1, f_W1, mus, Wb);

    dim3 grid(Nn, Bn);
    pair_kernel<<<grid, 256, 0, stream>>>(state, mus, gam,
        s1_W1, s1_b1, s1_W2, s1_b2,
        s2_W1, s2_b1, s2_W2, s2_b2,
        f_W1, f_b1, f_W2, f_b2,
        Wb, vx_pre, tr_part, out);

    finalize_kernel<<<Bn, 256, 0, stream>>>(vx_pre, tr_part, out);
}